// Round 19
// baseline (79.726 us; speedup 1.0000x reference)
//
#include <hip/hip_runtime.h>
#include <hip/hip_bf16.h>

#define B_  4
#define S_  8192
#define H_  256
#define C_  128
#define NC_ 64
#define M_  (B_*S_)

typedef unsigned short u16;
typedef __attribute__((ext_vector_type(8))) short short8;
typedef __attribute__((ext_vector_type(4))) float f32x4;
typedef __attribute__((address_space(1))) void gas_t;
typedef __attribute__((address_space(3))) void las_t;

static constexpr float L2G   = -0.045803690f;          // log2(0.96875)
static constexpr float ROPE2 = -0.103810253f;          // -(2/256)*log2(10000)

__device__ __forceinline__ u16 f2b(float x) {
  union { __hip_bfloat16 b; u16 u; } c; c.b = __float2bfloat16(x); return c.u;
}
__device__ __forceinline__ float b2f(u16 u) {
  union { u16 u; __hip_bfloat16 b; } c; c.u = u; return __bfloat162float(c.b);
}
__device__ __forceinline__ f32x4 mfma16(short8 a, short8 b, f32x4 c) {
  return __builtin_amdgcn_mfma_f32_16x16x32_bf16(a, b, c, 0, 0, 0);
}
#define PRIO_HI() __builtin_amdgcn_s_setprio(1)
#define PRIO_LO() __builtin_amdgcn_s_setprio(0)

// ---- fragment readers: swizzled rows, 16B-slot phys = keep-high | (low ^ sw(row)) ----
__device__ __forceinline__ int sw4(int row) { return (row ^ (row >> 2)) & 3; }
__device__ __forceinline__ short8 fr32(const u16* base, int row, int slot) {   // 256-col rows
  return *reinterpret_cast<const short8*>(base + row*256 + (((slot&24)|((slot&7)^(row&7)))<<3));
}
__device__ __forceinline__ short8 fr16(const u16* base, int row, int slot) {   // 128-col rows
  return *reinterpret_cast<const short8*>(base + row*128 + (((slot&8)|((slot&7)^(row&7)))<<3));
}
__device__ __forceinline__ short8 fr4(const u16* base, int row, int slot) {    // 32-col rows
  return *reinterpret_cast<const short8*>(base + row*32 + ((slot ^ sw4(row))<<3));
}
__device__ __forceinline__ short8 fragr(const u16* lds, int row, int slot) {   // 64-col rows
  return *reinterpret_cast<const short8*>(lds + row*64 + ((slot ^ (row & 7)) << 3));
}

// async [128 rows][64 cols] bf16 tile stage (256-thr), pre-swizzled source
__device__ __forceinline__ void stageA(const u16* __restrict__ src, int stride,
                                       u16* smbase, int off, int t) {
  #pragma unroll
  for (int it = 0; it < 4; ++it) {
    const int u = it*256 + t, row = u >> 3, lsl = (u & 7) ^ (row & 7);
    const u16* gp = src + (size_t)row*stride + lsl*8;
    u16* lp = smbase + off + it*2048 + (t & 192)*8;
    __builtin_amdgcn_global_load_lds((gas_t*)gp, (las_t*)lp, 16, 0, 0);
  }
}
// async W tile [256 n][32 k] bf16 stage (512-thr), linear LDS dest, inv-swizzled source
__device__ __forceinline__ void stageW(const u16* __restrict__ src, u16* dst, int t) {
  #pragma unroll
  for (int it = 0; it < 2; ++it) {
    const int u = it*512 + t, row = u >> 2, p = u & 3, s = p ^ sw4(row);
    const u16* gp = src + (size_t)row*256 + s*8;
    u16* lp = dst + (size_t)(it*512 + (t & ~63))*8;
    __builtin_amdgcn_global_load_lds((gas_t*)gp, (las_t*)lp, 16, 0, 0);
  }
}
// async W tile [256 rows][64 k] bf16 stage (512-thr), fragr-compatible swizzle
__device__ __forceinline__ void stageW64(const u16* __restrict__ src, int stride,
                                         u16* smbase, int off, int t) {
  #pragma unroll
  for (int it = 0; it < 4; ++it) {
    const int u = it*512 + t, row = u >> 3, lsl = (u & 7) ^ (row & 7);
    const u16* gp = src + (size_t)row*stride + lsl*8;
    u16* lp = smbase + off + it*4096 + (t & 448)*8;   // wave-uniform base
    __builtin_amdgcn_global_load_lds((gas_t*)gp, (las_t*)lp, 16, 0, 0);
  }
}

// ---------------- K0: prep — W -> transposed bf16 [z][n][k], RoPE table ----------------
__global__ __launch_bounds__(256) void prep(
    const float* __restrict__ Wq, const float* __restrict__ Wk,
    const float* __restrict__ Wv, u16* __restrict__ WhT, float* __restrict__ RTab)
{
  const int bid = blockIdx.x;
  if (bid < 96) {
    const int i = bid*256 + threadIdx.x;
    const int z = i >> 13, r = i & 8191;
    const int n = r >> 5, k0 = (r & 31) << 3;
    const float* W = (z == 0) ? Wq : (z == 1) ? Wk : Wv;
    u16 o[8];
    #pragma unroll
    for (int j = 0; j < 8; ++j) o[j] = f2b(W[(size_t)(k0 + j)*H_ + n]);
    *reinterpret_cast<uint4*>(WhT + ((size_t)z << 16) + n*H_ + k0) =
        *reinterpret_cast<uint4*>(o);
    return;
  }
  const int i = (bid - 96)*256 + threadIdx.x;    // 0..1048575
  const int s = i >> 7, h = i & 127;
  const float invf = exp2f(ROPE2 * (float)h);
  float sn, cs;
  sincosf((float)s * invf, &sn, &cs);
  *reinterpret_cast<float2*>(RTab + 2*((size_t)s*128 + h)) = make_float2(cs, sn);
}

// ---------------- K1: fused per-(b,chunk): Q+K fused GEMM, V W64, Sc, T ----------
__global__ __launch_bounds__(512, 2) void fused_chunk(
    const float* __restrict__ X, const u16* __restrict__ WhT,
    const float* __restrict__ RTab,
    u16* __restrict__ Qh, u16* __restrict__ Tt,
    u16* __restrict__ Scg, u16* __restrict__ VTg)
{
  __shared__ u16 SM[81920];   // 160 KB
  u16* XS = SM;
  u16* WB = SM + 32768;
  u16* RB = SM + 49152;
  const int t = threadIdx.x, l = t & 63, wid = t >> 6;
  const int g = l >> 4, l15 = l & 15;
  const int mr = wid >> 2, nq = wid & 3;        // GEMM wave grid: 2m x 4n
  const int c = blockIdx.x, b = blockIdx.y;
  const float* Xc = X + ((size_t)(b*S_ + c*C_))*H_;
  const float4* RT4 = reinterpret_cast<const float4*>(RTab);

  // ---- T0: issue (Wq,Wk) tile0 async, then reg-stage X chunk f32->bf16 into XS ----
  stageW(WhT + 0,     SM + 32768,        t);
  stageW(WhT + 65536, SM + 32768 + 8192, t);
  #pragma unroll
  for (int it = 0; it < 8; ++it) {
    const int u = it*512 + t, row = u >> 5, sl = u & 31;
    const float* p = Xc + (size_t)row*256 + sl*8;
    float4 a = *reinterpret_cast<const float4*>(p);
    float4 bb = *reinterpret_cast<const float4*>(p + 4);
    u16 o[8] = {f2b(a.x), f2b(a.y), f2b(a.z), f2b(a.w),
                f2b(bb.x), f2b(bb.y), f2b(bb.z), f2b(bb.w)};
    *reinterpret_cast<uint4*>(XS + row*256 + (((sl&24)|((sl&7)^(row&7)))<<3)) =
        *reinterpret_cast<uint4*>(o);
  }
  __syncthreads();

  // ---- T1: fused Q+K GEMM (both swapped: l15=m, regs=consec n); shared A frags ----
  f32x4 qa[4][4] = {}, ka[4][4] = {};
  for (int ks = 0; ks < 8; ++ks) {
    const u16* Wb = SM + 32768 + (ks&1)*16384;
    if (ks < 7) {
      u16* Wn = SM + 32768 + ((ks+1)&1)*16384;
      stageW(WhT + (ks+1)*32,         Wn,        t);
      stageW(WhT + 65536 + (ks+1)*32, Wn + 8192, t);
    }
    short8 a[4], bw[4];
    #pragma unroll
    for (int i = 0; i < 4; ++i) a[i] = fr32(XS, mr*64 + i*16 + l15, ks*4 + g);
    #pragma unroll
    for (int j = 0; j < 4; ++j) bw[j] = fr4(Wb, nq*64 + j*16 + l15, g);
    PRIO_HI();
    #pragma unroll
    for (int i = 0; i < 4; ++i)
      #pragma unroll
      for (int j = 0; j < 4; ++j)
        qa[i][j] = mfma16(bw[j], a[i], qa[i][j]);
    PRIO_LO();
    #pragma unroll
    for (int j = 0; j < 4; ++j) bw[j] = fr4(Wb + 8192, nq*64 + j*16 + l15, g);
    PRIO_HI();
    #pragma unroll
    for (int i = 0; i < 4; ++i)
      #pragma unroll
      for (int j = 0; j < 4; ++j)
        ka[i][j] = mfma16(bw[j], a[i], ka[i][j]);
    PRIO_LO();
    __syncthreads();
  }

  // ---- rope Q and K (in-lane; lane holds (m, n0..n0+3) = 2 pairs each) ----
  #pragma unroll
  for (int i = 0; i < 4; ++i) {
    const int s = c*C_ + mr*64 + i*16 + l15;
    #pragma unroll
    for (int j = 0; j < 4; ++j) {
      const int n0 = nq*64 + j*16 + g*4;
      const float4 tb = RT4[(size_t)s*64 + (n0 >> 2)];
      float x0 = qa[i][j][0], x1 = qa[i][j][1], x2 = qa[i][j][2], x3 = qa[i][j][3];
      qa[i][j][0] = x0*tb.x - x1*tb.y;  qa[i][j][1] = x1*tb.x + x0*tb.y;
      qa[i][j][2] = x2*tb.z - x3*tb.w;  qa[i][j][3] = x3*tb.z + x2*tb.w;
      x0 = ka[i][j][0]; x1 = ka[i][j][1]; x2 = ka[i][j][2]; x3 = ka[i][j][3];
      ka[i][j][0] = x0*tb.x - x1*tb.y;  ka[i][j][1] = x1*tb.x + x0*tb.y;
      ka[i][j][2] = x2*tb.z - x3*tb.w;  ka[i][j][3] = x3*tb.z + x2*tb.w;
    }
  }
  // restage Q_rm [128 m][256 n] into RB (QK dbuf dead after final loop barrier)
  #pragma unroll
  for (int i = 0; i < 4; ++i) {
    const int m = mr*64 + i*16 + l15;
    #pragma unroll
    for (int j = 0; j < 4; ++j) {
      const int n0 = nq*64 + j*16 + g*4;
      ushort4 pk;
      pk.x = f2b(qa[i][j][0]); pk.y = f2b(qa[i][j][1]);
      pk.z = f2b(qa[i][j][2]); pk.w = f2b(qa[i][j][3]);
      const int sl = n0 >> 3;
      *reinterpret_cast<ushort4*>(RB + m*256 + (((sl&24)|((sl&7)^(m&7)))<<3) + (n0&7)) = pk;
    }
  }
  __syncthreads();
  // coalesced Qh store
  #pragma unroll
  for (int it = 0; it < 8; ++it) {
    const int u = it*512 + t, row = u >> 5, sl = u & 31;
    uint4 v = *reinterpret_cast<const uint4*>(RB + row*256 + (((sl&24)|((sl&7)^(row&7)))<<3));
    *reinterpret_cast<uint4*>(Qh + ((size_t)(b*S_ + c*C_ + row))*H_ + sl*8) = v;
  }

  // ---- T5: Sc-GEMM in two d-halves; K_rm half staged via WB ----
  const int smh = wid >> 2, sn0 = (wid & 3)*32;   // Sc wave grid: 2m x 4n(32)
  f32x4 sc[4][2] = {};
  #pragma unroll
  for (int h = 0; h < 2; ++h) {
    if (((wid >> 1) & 1) == h) {   // waves nq in {2h, 2h+1} hold this d-half
      #pragma unroll
      for (int i = 0; i < 4; ++i) {
        const int m = mr*64 + i*16 + l15;
        #pragma unroll
        for (int j = 0; j < 4; ++j) {
          const int dl0 = (nq&1)*64 + j*16 + g*4;
          ushort4 pk;
          pk.x = f2b(ka[i][j][0]); pk.y = f2b(ka[i][j][1]);
          pk.z = f2b(ka[i][j][2]); pk.w = f2b(ka[i][j][3]);
          const int sl = dl0 >> 3;
          *reinterpret_cast<ushort4*>(WB + m*128 + (((sl&8)|((sl&7)^(m&7)))<<3) + (dl0&7)) = pk;
        }
      }
    }
    __syncthreads();
    PRIO_HI();
    #pragma unroll
    for (int kk = 0; kk < 4; ++kk) {
      short8 fa[4], fb[2];
      #pragma unroll
      for (int i = 0; i < 4; ++i) fa[i] = fr16(WB, smh*64 + i*16 + l15, kk*4 + g);
      #pragma unroll
      for (int j = 0; j < 2; ++j) fb[j] = fr32(RB, sn0 + j*16 + l15, h*16 + kk*4 + g);
      #pragma unroll
      for (int i = 0; i < 4; ++i)
        #pragma unroll
        for (int j = 0; j < 2; ++j)
          sc[i][j] = mfma16(fa[i], fb[j], sc[i][j]);
    }
    PRIO_LO();
    __syncthreads();
  }
  // V tile0 prefetch into RB buf0 (Q_rm dead after Sc's final barrier);
  // flies under mask/decay VALU + barrier
  stageW64(WhT + 2*65536, H_, SM, 49152, t);
  // mask + decay -> Sc [128 n][128 m] bf16 into WB (reads done at last barrier)
  #pragma unroll
  for (int j = 0; j < 2; ++j) {
    const int n = sn0 + j*16 + l15;
    #pragma unroll
    for (int i = 0; i < 4; ++i) {
      const int m0 = smh*64 + i*16 + g*4;
      ushort4 pk;
      #pragma unroll
      for (int r = 0; r < 4; ++r) {
        const int m = m0 + r;
        const float sv = (n >= m) ? sc[i][j][r] * exp2f((float)(n - m)*L2G) : 0.f;
        reinterpret_cast<u16*>(&pk)[r] = f2b(sv);
      }
      const int sl = m0 >> 3;
      *reinterpret_cast<ushort4*>(WB + n*128 + (((sl&8)|((sl&7)^(n&7)))<<3) + (m0&7)) = pk;
    }
  }
  __syncthreads();

  // ---- T7: V-GEMM (normal: l15=n(j), regs=consec m); 4x 64k-wide tiles in RB ----
  f32x4 va[4][4] = {};
  for (int kt = 0; kt < 4; ++kt) {
    const u16* Wcur = SM + 49152 + (kt&1)*16384;
    if (kt < 3) stageW64(WhT + 2*65536 + (kt+1)*64, H_, SM, 49152 + ((kt+1)&1)*16384, t);
    #pragma unroll
    for (int kb = 0; kb < 2; ++kb) {
      short8 a[4], bw[4];
      #pragma unroll
      for (int i = 0; i < 4; ++i) a[i] = fr32(XS, mr*64 + i*16 + l15, kt*8 + kb*4 + g);
      #pragma unroll
      for (int j = 0; j < 4; ++j) bw[j] = fragr(Wcur, nq*64 + j*16 + l15, kb*4 + g);
      PRIO_HI();
      #pragma unroll
      for (int i = 0; i < 4; ++i)
        #pragma unroll
        for (int j = 0; j < 4; ++j)
          va[i][j] = mfma16(a[i], bw[j], va[i][j]);
      PRIO_LO();
    }
    __syncthreads();
  }

  // ---- Sc global store (WB stable; ordered by T7 barriers) ----
  {
    const size_t scb = ((size_t)(b*NC_ + c)) << 14;
    #pragma unroll
    for (int it = 0; it < 4; ++it) {
      const int u = it*512 + t, row = u >> 4, sl = u & 15;
      uint4 v = *reinterpret_cast<const uint4*>(WB + row*128 + (((sl&8)|((sl&7)^(row&7)))<<3));
      *reinterpret_cast<uint4*>(Scg + scb + (size_t)row*128 + sl*8) = v;
    }
  }

  // ---- T8: VT [256 j][128 m] -> RB; KTw [256 d][128 m] (decay-weighted K) -> XS ----
  #pragma unroll
  for (int jj = 0; jj < 4; ++jj) {
    const int j = nq*64 + jj*16 + l15;
    #pragma unroll
    for (int i = 0; i < 4; ++i) {
      const int m0 = mr*64 + i*16 + g*4;
      ushort4 pk;
      pk.x = f2b(va[i][jj][0]); pk.y = f2b(va[i][jj][1]);
      pk.z = f2b(va[i][jj][2]); pk.w = f2b(va[i][jj][3]);
      const int sl = m0 >> 3;
      *reinterpret_cast<ushort4*>(RB + j*128 + (((sl&8)|((sl&7)^(j&7)))<<3) + (m0&7)) = pk;
    }
  }
  #pragma unroll
  for (int i = 0; i < 4; ++i) {
    const int m = mr*64 + i*16 + l15;
    const float wd = exp2f((float)(C_ - 1 - m)*L2G);
    const int slm = m >> 3;
    #pragma unroll
    for (int jj = 0; jj < 4; ++jj) {
      #pragma unroll
      for (int r = 0; r < 4; ++r) {
        const int d = nq*64 + jj*16 + g*4 + r;
        XS[d*128 + (((slm&8)|((slm&7)^(d&7)))<<3) + (m&7)] = f2b(ka[i][jj][r] * wd);
      }
    }
  }
  __syncthreads();

  // ---- T9: T-GEMM  T[j][i] = sum_m VT[j,m]*KTw[i,m]  (l15=j, regs=consec i) ----
  const int ih = wid & 1, jq = wid >> 1;
  {
    f32x4 tt[8][4] = {};
    PRIO_HI();
    #pragma unroll
    for (int kk = 0; kk < 4; ++kk) {
      short8 fk[8], fv[4];
      #pragma unroll
      for (int ii = 0; ii < 8; ++ii) fk[ii] = fr16(XS, ih*128 + ii*16 + l15, kk*4 + g);
      #pragma unroll
      for (int jj = 0; jj < 4; ++jj) fv[jj] = fr16(RB, jq*64 + jj*16 + l15, kk*4 + g);
      #pragma unroll
      for (int ii = 0; ii < 8; ++ii)
        #pragma unroll
        for (int jj = 0; jj < 4; ++jj)
          tt[ii][jj] = mfma16(fk[ii], fv[jj], tt[ii][jj]);
    }
    PRIO_LO();
    __syncthreads();   // all KTw/VT reads done before XS reuse

    // VT global store (RB stable from here on)
    {
      const size_t vtb = ((size_t)(b*NC_ + c)) << 15;
      #pragma unroll
      for (int it = 0; it < 8; ++it) {
        const int u = it*512 + t, row = u >> 4, sl = u & 15;
        uint4 v = *reinterpret_cast<const uint4*>(RB + row*128 + (((sl&8)|((sl&7)^(row&7)))<<3));
        *reinterpret_cast<uint4*>(VTg + vtb + (size_t)row*128 + sl*8) = v;
      }
    }

    const size_t tb = ((size_t)(b*NC_ + c)) << 16;
    #pragma unroll
    for (int p = 0; p < 2; ++p) {
      if ((jq >> 1) == p) {
        #pragma unroll
        for (int ii = 0; ii < 8; ++ii)
          #pragma unroll
          for (int jj = 0; jj < 4; ++jj) {
            const int jl = (jq&1)*64 + jj*16 + l15;
            const int i0 = ih*128 + ii*16 + g*4;
            ushort4 pk;
            pk.x = f2b(tt[ii][jj][0]); pk.y = f2b(tt[ii][jj][1]);
            pk.z = f2b(tt[ii][jj][2]); pk.w = f2b(tt[ii][jj][3]);
            const int sl = i0 >> 3;
            *reinterpret_cast<ushort4*>(XS + jl*256 + (((sl&24)|((sl&7)^(jl&7)))<<3) + (i0&7)) = pk;
          }
      }
      __syncthreads();
      #pragma unroll
      for (int it = 0; it < 8; ++it) {
        const int u = it*512 + t, row = u >> 5, sl = u & 31;
        uint4 v = *reinterpret_cast<const uint4*>(XS + row*256 + (((sl&24)|((sl&7)^(row&7)))<<3));
        *reinterpret_cast<uint4*>(Tt + tb + (size_t)(p*128 + row)*256 + sl*8) = v;
      }
      __syncthreads();
    }
  }
}

// ---------------- K2: exclusive scan: state[c] = g^C state[c-1] + T[c-1] ----------------
__global__ __launch_bounds__(256) void scan_state(u16* __restrict__ Tt)
{
  const unsigned e = blockIdx.x*256u + threadIdx.x;   // B_*32768 threads, 2 elems each
  const unsigned b = e >> 15, el = (e & 32767u) << 1;
  const float gC = exp2f(128.0f * L2G);
  float r0 = 0.f, r1 = 0.f;
  const size_t base = (((size_t)b * NC_) << 16) + el;
  #pragma unroll
  for (int grp = 0; grp < 4; ++grp) {
    unsigned buf[16];
    #pragma unroll
    for (int i2 = 0; i2 < 16; ++i2)
      buf[i2] = *reinterpret_cast<const unsigned*>(Tt + base + (size_t)(grp*16 + i2)*65536);
    #pragma unroll
    for (int i2 = 0; i2 < 16; ++i2) {
      const unsigned v = buf[i2];
      *reinterpret_cast<unsigned*>(Tt + base + (size_t)(grp*16 + i2)*65536) =
          (unsigned)f2b(r0) | ((unsigned)f2b(r1) << 16);
      r0 = fmaf(gC, r0, b2f((u16)(v & 0xffff)));
      r1 = fmaf(gC, r1, b2f((u16)(v >> 16)));
    }
  }
}

// ---------------- K3: Out = g^(n+1)*(Q @ state) + Sc·V  (no Oloc round trip) ----------
__global__ __launch_bounds__(256) void out_kernel(
    const u16* __restrict__ Qh, const u16* __restrict__ Tt,
    const u16* __restrict__ Scg, const u16* __restrict__ VTg,
    float* __restrict__ Out)
{
  __shared__ u16 SM[32768];   // 64 KB -> 2 blocks/CU
  const int t = threadIdx.x, l = t & 63, wid = t >> 6;
  const int wr = wid >> 1, wc = wid & 1, g = l >> 4, l15 = l & 15;
  const int c = blockIdx.x, b = blockIdx.y, jh = blockIdx.z;
  const u16* Asrc = Qh + (size_t)(b*S_ + c*C_)*H_;
  const u16* Bsrc = Tt + (((size_t)(b*NC_ + c)) << 16) + (size_t)(jh*128)*H_;
  f32x4 acc[4][4] = {};

  // ---- phase A: cross GEMM (contraction over d=256) ----
  stageA(Asrc, H_, SM, 0, t);
  stageA(Bsrc, H_, SM, 8192, t);
  __syncthreads();
  for (int ks = 0; ks < 4; ++ks) {
    const int cur = (ks & 1) * 16384;
    if (ks < 3) {
      stageA(Asrc + (ks+1)*64, H_, SM, 16384 - cur, t);
      stageA(Bsrc + (ks+1)*64, H_, SM, 16384 - cur + 8192, t);
    }
    #pragma unroll
    for (int kb = 0; kb < 2; ++kb) {
      short8 fq[4], ft[4];
      #pragma unroll
      for (int i = 0; i < 4; ++i) fq[i] = fragr(SM + cur, wr*64 + i*16 + l15, kb*4 + g);
      #pragma unroll
      for (int j = 0; j < 4; ++j) ft[j] = fragr(SM + cur + 8192, wc*64 + j*16 + l15, kb*4 + g);
      #pragma unroll
      for (int i = 0; i < 4; ++i)
        #pragma unroll
        for (int j = 0; j < 4; ++j)
          acc[i][j] = mfma16(ft[j], fq[i], acc[i][j]);   // l15=n, regs=consec j
    }
    __syncthreads();
  }

  // ---- phase B staging: Sc [128 n][128 m], VT half [128 j][128 m] ----
  const u16* ScC = Scg + (((size_t)(b*NC_ + c)) << 14);
  const u16* VtC = VTg + (((size_t)(b*NC_ + c)) << 15) + (size_t)(jh*128)*128;
  stageA(ScC,      128, SM, 0,     t);
  stageA(VtC,      128, SM, 8192,  t);
  stageA(ScC + 64, 128, SM, 16384, t);
  stageA(VtC + 64, 128, SM, 24576, t);
  // scale cross term by gamma^(n_local+1) while loads fly
  #pragma unroll
  for (int i = 0; i < 4; ++i) {
    const float gn = exp2f((float)(wr*64 + i*16 + l15 + 1) * L2G);
    #pragma unroll
    for (int j = 0; j < 4; ++j)
      #pragma unroll
      for (int r = 0; r < 4; ++r) acc[i][j][r] *= gn;
  }
  __syncthreads();

  // ---- phase B: local GEMM (contraction over m=128) ----
  #pragma unroll
  for (int ks2 = 0; ks2 < 2; ++ks2) {
    #pragma unroll
    for (int kb = 0; kb < 2; ++kb) {
      short8 fs[4], fv[4];
      #pragma unroll
      for (int i = 0; i < 4; ++i)
        fs[i] = fragr(SM + ks2*16384, wr*64 + i*16 + l15, kb*4 + g);          // Sc rows n
      #pragma unroll
      for (int j = 0; j < 4; ++j)
        fv[j] = fragr(SM + ks2*16384 + 8192, wc*64 + j*16 + l15, kb*4 + g);   // VT rows j
      #pragma unroll
      for (int i = 0; i < 4; ++i)
        #pragma unroll
        for (int j = 0; j < 4; ++j)
          acc[i][j] = mfma16(fv[j], fs[i], acc[i][j]);
    }
  }
  __syncthreads();

  // ---- epilogue: restage [64 n][128 j] f32, coalesced Out store ----
  float* OL = reinterpret_cast<float*>(SM);
  for (int ph = 0; ph < 2; ++ph) {
    if (wr == ph) {
      #pragma unroll
      for (int i = 0; i < 4; ++i) {
        const int nl = i*16 + l15;
        #pragma unroll
        for (int j = 0; j < 4; ++j) {
          const int j0 = wc*64 + j*16 + g*4;
          const int sl = j0 >> 2;
          *reinterpret_cast<f32x4*>(OL + nl*128 + (((sl&24)|((sl&7)^(nl&7)))<<2)) = acc[i][j];
        }
      }
    }
    __syncthreads();
    #pragma unroll
    for (int it = 0; it < 8; ++it) {
      const int u = it*256 + t, nl = u >> 5, sl = u & 31;
      f32x4 v = *reinterpret_cast<const f32x4*>(OL + nl*128 + (((sl&24)|((sl&7)^(nl&7)))<<2));
      const size_t off = ((size_t)(b*S_ + c*C_ + ph*64 + nl))*256 + jh*128 + sl*4;
      *reinterpret_cast<f32x4*>(Out + off) = v;
    }
    __syncthreads();
  }
}

extern "C" void kernel_launch(void* const* d_in, const int* in_sizes, int n_in,
                              void* d_out, int out_size, void* d_ws, size_t ws_size,
                              hipStream_t stream) {
  const float* X  = (const float*)d_in[0];
  const float* Wq = (const float*)d_in[1];
  const float* Wk = (const float*)d_in[2];
  const float* Wv = (const float*)d_in[3];
  float* Out = (float*)d_out;
  u16* ws = (u16*)d_ws;
  // workspace (u16): WhT 196608 | RTab 4194304 | Qh 8388608 | Tt 16777216 | Scg 4194304 | VTg 8388608
  u16*   WhT  = ws;
  float* RTab = (float*)(ws + 196608);
  u16*   Qh   = ws + 196608 + 4194304;
  u16*   Tt   = Qh + (size_t)M_*H_;
  u16*   Scg  = Tt + (size_t)B_*NC_*65536;
  u16*   VTg  = Scg + (size_t)B_*NC_*16384;

  prep<<<96 + 4096, 256, 0, stream>>>(Wq, Wk, Wv, WhT, RTab);
  fused_chunk<<<dim3(NC_, B_), 512, 0, stream>>>(X, WhT, RTab, Qh, Tt, Scg, VTg);
  scan_state<<<(B_*32768)/256, 256, 0, stream>>>(Tt);
  out_kernel<<<dim3(NC_, B_, 2), 256, 0, stream>>>(Qh, Tt, Scg, VTg, Out);
}

// Round 20
// 78.503 us; speedup vs baseline: 1.0156x; 1.0156x over previous
//
#include <hip/hip_runtime.h>
#include <hip/hip_bf16.h>

#define B_  4
#define S_  8192
#define H_  256
#define C_  128
#define NC_ 64
#define M_  (B_*S_)

typedef unsigned short u16;
typedef __attribute__((ext_vector_type(8))) short short8;
typedef __attribute__((ext_vector_type(4))) float f32x4;
typedef __attribute__((address_space(1))) void gas_t;
typedef __attribute__((address_space(3))) void las_t;

static constexpr float L2G   = -0.045803690f;          // log2(0.96875)
static constexpr float ROPE2 = -0.103810253f;          // -(2/256)*log2(10000)

__device__ __forceinline__ u16 f2b(float x) {
  union { __hip_bfloat16 b; u16 u; } c; c.b = __float2bfloat16(x); return c.u;
}
__device__ __forceinline__ float b2f(u16 u) {
  union { u16 u; __hip_bfloat16 b; } c; c.u = u; return __bfloat162float(c.b);
}
__device__ __forceinline__ f32x4 mfma16(short8 a, short8 b, f32x4 c) {
  return __builtin_amdgcn_mfma_f32_16x16x32_bf16(a, b, c, 0, 0, 0);
}

// ---- fragment readers: swizzled rows, 16B-slot phys = keep-high | (low ^ sw(row)) ----
__device__ __forceinline__ int sw4(int row) { return (row ^ (row >> 2)) & 3; }
__device__ __forceinline__ short8 fr32(const u16* base, int row, int slot) {   // 256-col rows
  return *reinterpret_cast<const short8*>(base + row*256 + (((slot&24)|((slot&7)^(row&7)))<<3));
}
__device__ __forceinline__ short8 fr16(const u16* base, int row, int slot) {   // 128-col rows
  return *reinterpret_cast<const short8*>(base + row*128 + (((slot&8)|((slot&7)^(row&7)))<<3));
}
__device__ __forceinline__ short8 fr4(const u16* base, int row, int slot) {    // 32-col rows
  return *reinterpret_cast<const short8*>(base + row*32 + ((slot ^ sw4(row))<<3));
}
__device__ __forceinline__ short8 fragr(const u16* lds, int row, int slot) {   // 64-col rows
  return *reinterpret_cast<const short8*>(lds + row*64 + ((slot ^ (row & 7)) << 3));
}

// async [128 rows][64 cols] bf16 tile stage (256-thr), pre-swizzled source
__device__ __forceinline__ void stageA(const u16* __restrict__ src, int stride,
                                       u16* smbase, int off, int t) {
  #pragma unroll
  for (int it = 0; it < 4; ++it) {
    const int u = it*256 + t, row = u >> 3, lsl = (u & 7) ^ (row & 7);
    const u16* gp = src + (size_t)row*stride + lsl*8;
    u16* lp = smbase + off + it*2048 + (t & 192)*8;
    __builtin_amdgcn_global_load_lds((gas_t*)gp, (las_t*)lp, 16, 0, 0);
  }
}
// async W tile [256 n][32 k] bf16 stage (512-thr), linear LDS dest, inv-swizzled source
__device__ __forceinline__ void stageW(const u16* __restrict__ src, u16* dst, int t) {
  #pragma unroll
  for (int it = 0; it < 2; ++it) {
    const int u = it*512 + t, row = u >> 2, p = u & 3, s = p ^ sw4(row);
    const u16* gp = src + (size_t)row*256 + s*8;
    u16* lp = dst + (size_t)(it*512 + (t & ~63))*8;
    __builtin_amdgcn_global_load_lds((gas_t*)gp, (las_t*)lp, 16, 0, 0);
  }
}
// async W tile [256 rows][64 k] bf16 stage (512-thr), fragr-compatible swizzle
__device__ __forceinline__ void stageW64(const u16* __restrict__ src, int stride,
                                         u16* smbase, int off, int t) {
  #pragma unroll
  for (int it = 0; it < 4; ++it) {
    const int u = it*512 + t, row = u >> 3, lsl = (u & 7) ^ (row & 7);
    const u16* gp = src + (size_t)row*stride + lsl*8;
    u16* lp = smbase + off + it*4096 + (t & 448)*8;   // wave-uniform base
    __builtin_amdgcn_global_load_lds((gas_t*)gp, (las_t*)lp, 16, 0, 0);
  }
}

// ---------------- K0: prep — W -> transposed bf16 [z][n][k], RoPE table ----------------
__global__ __launch_bounds__(256) void prep(
    const float* __restrict__ Wq, const float* __restrict__ Wk,
    const float* __restrict__ Wv, u16* __restrict__ WhT, float* __restrict__ RTab)
{
  const int bid = blockIdx.x;
  if (bid < 96) {
    const int i = bid*256 + threadIdx.x;
    const int z = i >> 13, r = i & 8191;
    const int n = r >> 5, k0 = (r & 31) << 3;
    const float* W = (z == 0) ? Wq : (z == 1) ? Wk : Wv;
    u16 o[8];
    #pragma unroll
    for (int j = 0; j < 8; ++j) o[j] = f2b(W[(size_t)(k0 + j)*H_ + n]);
    *reinterpret_cast<uint4*>(WhT + ((size_t)z << 16) + n*H_ + k0) =
        *reinterpret_cast<uint4*>(o);
    return;
  }
  const int i = (bid - 96)*256 + threadIdx.x;    // 0..1048575
  const int s = i >> 7, h = i & 127;
  const float invf = exp2f(ROPE2 * (float)h);
  float sn, cs;
  sincosf((float)s * invf, &sn, &cs);
  *reinterpret_cast<float2*>(RTab + 2*((size_t)s*128 + h)) = make_float2(cs, sn);
}

// ---------------- K1: fused per-(b,chunk): Q+K fused GEMM, V W64, Sc, T ----------
// LDS (u16 idx): XS [0,32768) = X [128 m][256 d]; later KTw; later T restage
//                QK dbuf [32768,65536) = 2 x {Wq-tile(8192), Wk-tile(8192)}
//                WB [32768,49152) = K_rm half / Sc (after QK loop)
//                RB [49152,81920) = Q_rm [128 m][256 n] (after QK loop);
//                                   later V W64 dbuf; later VT [256 j][128 m]
__global__ __launch_bounds__(512, 2) void fused_chunk(
    const float* __restrict__ X, const u16* __restrict__ WhT,
    const float* __restrict__ RTab,
    u16* __restrict__ Qh, u16* __restrict__ Tt,
    u16* __restrict__ Scg, u16* __restrict__ VTg)
{
  __shared__ u16 SM[81920];   // 160 KB
  u16* XS = SM;
  u16* WB = SM + 32768;
  u16* RB = SM + 49152;
  const int t = threadIdx.x, l = t & 63, wid = t >> 6;
  const int g = l >> 4, l15 = l & 15;
  const int mr = wid >> 2, nq = wid & 3;        // GEMM wave grid: 2m x 4n
  const int c = blockIdx.x, b = blockIdx.y;
  const float* Xc = X + ((size_t)(b*S_ + c*C_))*H_;
  const float4* RT4 = reinterpret_cast<const float4*>(RTab);

  // ---- T0: issue (Wq,Wk) tile0 async, then reg-stage X chunk f32->bf16 into XS ----
  stageW(WhT + 0,     SM + 32768,        t);
  stageW(WhT + 65536, SM + 32768 + 8192, t);
  #pragma unroll
  for (int it = 0; it < 8; ++it) {
    const int u = it*512 + t, row = u >> 5, sl = u & 31;
    const float* p = Xc + (size_t)row*256 + sl*8;
    float4 a = *reinterpret_cast<const float4*>(p);
    float4 bb = *reinterpret_cast<const float4*>(p + 4);
    u16 o[8] = {f2b(a.x), f2b(a.y), f2b(a.z), f2b(a.w),
                f2b(bb.x), f2b(bb.y), f2b(bb.z), f2b(bb.w)};
    *reinterpret_cast<uint4*>(XS + row*256 + (((sl&24)|((sl&7)^(row&7)))<<3)) =
        *reinterpret_cast<uint4*>(o);
  }
  __syncthreads();

  // ---- T1: fused Q+K GEMM (both swapped: l15=m, regs=consec n); shared A frags ----
  f32x4 qa[4][4] = {}, ka[4][4] = {};
  for (int ks = 0; ks < 8; ++ks) {
    const u16* Wb = SM + 32768 + (ks&1)*16384;
    if (ks < 7) {
      u16* Wn = SM + 32768 + ((ks+1)&1)*16384;
      stageW(WhT + (ks+1)*32,         Wn,        t);
      stageW(WhT + 65536 + (ks+1)*32, Wn + 8192, t);
    }
    short8 a[4], bw[4];
    #pragma unroll
    for (int i = 0; i < 4; ++i) a[i] = fr32(XS, mr*64 + i*16 + l15, ks*4 + g);
    #pragma unroll
    for (int j = 0; j < 4; ++j) bw[j] = fr4(Wb, nq*64 + j*16 + l15, g);
    #pragma unroll
    for (int i = 0; i < 4; ++i)
      #pragma unroll
      for (int j = 0; j < 4; ++j)
        qa[i][j] = mfma16(bw[j], a[i], qa[i][j]);
    #pragma unroll
    for (int j = 0; j < 4; ++j) bw[j] = fr4(Wb + 8192, nq*64 + j*16 + l15, g);
    #pragma unroll
    for (int i = 0; i < 4; ++i)
      #pragma unroll
      for (int j = 0; j < 4; ++j)
        ka[i][j] = mfma16(bw[j], a[i], ka[i][j]);
    __syncthreads();
  }

  // ---- rope Q and K (in-lane; lane holds (m, n0..n0+3) = 2 pairs each) ----
  #pragma unroll
  for (int i = 0; i < 4; ++i) {
    const int s = c*C_ + mr*64 + i*16 + l15;
    #pragma unroll
    for (int j = 0; j < 4; ++j) {
      const int n0 = nq*64 + j*16 + g*4;
      const float4 tb = RT4[(size_t)s*64 + (n0 >> 2)];
      float x0 = qa[i][j][0], x1 = qa[i][j][1], x2 = qa[i][j][2], x3 = qa[i][j][3];
      qa[i][j][0] = x0*tb.x - x1*tb.y;  qa[i][j][1] = x1*tb.x + x0*tb.y;
      qa[i][j][2] = x2*tb.z - x3*tb.w;  qa[i][j][3] = x3*tb.z + x2*tb.w;
      x0 = ka[i][j][0]; x1 = ka[i][j][1]; x2 = ka[i][j][2]; x3 = ka[i][j][3];
      ka[i][j][0] = x0*tb.x - x1*tb.y;  ka[i][j][1] = x1*tb.x + x0*tb.y;
      ka[i][j][2] = x2*tb.z - x3*tb.w;  ka[i][j][3] = x3*tb.z + x2*tb.w;
    }
  }
  // restage Q_rm [128 m][256 n] into RB (QK dbuf dead after final loop barrier)
  #pragma unroll
  for (int i = 0; i < 4; ++i) {
    const int m = mr*64 + i*16 + l15;
    #pragma unroll
    for (int j = 0; j < 4; ++j) {
      const int n0 = nq*64 + j*16 + g*4;
      ushort4 pk;
      pk.x = f2b(qa[i][j][0]); pk.y = f2b(qa[i][j][1]);
      pk.z = f2b(qa[i][j][2]); pk.w = f2b(qa[i][j][3]);
      const int sl = n0 >> 3;
      *reinterpret_cast<ushort4*>(RB + m*256 + (((sl&24)|((sl&7)^(m&7)))<<3) + (n0&7)) = pk;
    }
  }
  __syncthreads();
  // coalesced Qh store
  #pragma unroll
  for (int it = 0; it < 8; ++it) {
    const int u = it*512 + t, row = u >> 5, sl = u & 31;
    uint4 v = *reinterpret_cast<const uint4*>(RB + row*256 + (((sl&24)|((sl&7)^(row&7)))<<3));
    *reinterpret_cast<uint4*>(Qh + ((size_t)(b*S_ + c*C_ + row))*H_ + sl*8) = v;
  }

  // ---- T5: Sc-GEMM in two d-halves; K_rm half staged via WB ----
  const int smh = wid >> 2, sn0 = (wid & 3)*32;   // Sc wave grid: 2m x 4n(32)
  f32x4 sc[4][2] = {};
  #pragma unroll
  for (int h = 0; h < 2; ++h) {
    if (((wid >> 1) & 1) == h) {   // waves nq in {2h, 2h+1} hold this d-half
      #pragma unroll
      for (int i = 0; i < 4; ++i) {
        const int m = mr*64 + i*16 + l15;
        #pragma unroll
        for (int j = 0; j < 4; ++j) {
          const int dl0 = (nq&1)*64 + j*16 + g*4;
          ushort4 pk;
          pk.x = f2b(ka[i][j][0]); pk.y = f2b(ka[i][j][1]);
          pk.z = f2b(ka[i][j][2]); pk.w = f2b(ka[i][j][3]);
          const int sl = dl0 >> 3;
          *reinterpret_cast<ushort4*>(WB + m*128 + (((sl&8)|((sl&7)^(m&7)))<<3) + (dl0&7)) = pk;
        }
      }
    }
    __syncthreads();
    #pragma unroll
    for (int kk = 0; kk < 4; ++kk) {
      short8 fa[4], fb[2];
      #pragma unroll
      for (int i = 0; i < 4; ++i) fa[i] = fr16(WB, smh*64 + i*16 + l15, kk*4 + g);
      #pragma unroll
      for (int j = 0; j < 2; ++j) fb[j] = fr32(RB, sn0 + j*16 + l15, h*16 + kk*4 + g);
      #pragma unroll
      for (int i = 0; i < 4; ++i)
        #pragma unroll
        for (int j = 0; j < 2; ++j)
          sc[i][j] = mfma16(fa[i], fb[j], sc[i][j]);
    }
    __syncthreads();
  }
  // V tile0 prefetch into RB buf0 (Q_rm dead after Sc's final barrier);
  // flies under mask/decay VALU + barrier
  stageW64(WhT + 2*65536, H_, SM, 49152, t);
  // mask + decay -> Sc [128 n][128 m] bf16 into WB (reads done at last barrier)
  #pragma unroll
  for (int j = 0; j < 2; ++j) {
    const int n = sn0 + j*16 + l15;
    #pragma unroll
    for (int i = 0; i < 4; ++i) {
      const int m0 = smh*64 + i*16 + g*4;
      ushort4 pk;
      #pragma unroll
      for (int r = 0; r < 4; ++r) {
        const int m = m0 + r;
        const float sv = (n >= m) ? sc[i][j][r] * exp2f((float)(n - m)*L2G) : 0.f;
        reinterpret_cast<u16*>(&pk)[r] = f2b(sv);
      }
      const int sl = m0 >> 3;
      *reinterpret_cast<ushort4*>(WB + n*128 + (((sl&8)|((sl&7)^(n&7)))<<3) + (m0&7)) = pk;
    }
  }
  __syncthreads();

  // ---- T7: V-GEMM (normal: l15=n(j), regs=consec m); 4x 64k-wide tiles in RB ----
  f32x4 va[4][4] = {};
  for (int kt = 0; kt < 4; ++kt) {
    const u16* Wcur = SM + 49152 + (kt&1)*16384;
    if (kt < 3) stageW64(WhT + 2*65536 + (kt+1)*64, H_, SM, 49152 + ((kt+1)&1)*16384, t);
    #pragma unroll
    for (int kb = 0; kb < 2; ++kb) {
      short8 a[4], bw[4];
      #pragma unroll
      for (int i = 0; i < 4; ++i) a[i] = fr32(XS, mr*64 + i*16 + l15, kt*8 + kb*4 + g);
      #pragma unroll
      for (int j = 0; j < 4; ++j) bw[j] = fragr(Wcur, nq*64 + j*16 + l15, kb*4 + g);
      #pragma unroll
      for (int i = 0; i < 4; ++i)
        #pragma unroll
        for (int j = 0; j < 4; ++j)
          va[i][j] = mfma16(a[i], bw[j], va[i][j]);
    }
    __syncthreads();
  }

  // ---- Sc global store (WB stable; ordered by T7 barriers) ----
  {
    const size_t scb = ((size_t)(b*NC_ + c)) << 14;
    #pragma unroll
    for (int it = 0; it < 4; ++it) {
      const int u = it*512 + t, row = u >> 4, sl = u & 15;
      uint4 v = *reinterpret_cast<const uint4*>(WB + row*128 + (((sl&8)|((sl&7)^(row&7)))<<3));
      *reinterpret_cast<uint4*>(Scg + scb + (size_t)row*128 + sl*8) = v;
    }
  }

  // ---- T8: VT [256 j][128 m] -> RB; KTw [256 d][128 m] (decay-weighted K) -> XS ----
  #pragma unroll
  for (int jj = 0; jj < 4; ++jj) {
    const int j = nq*64 + jj*16 + l15;
    #pragma unroll
    for (int i = 0; i < 4; ++i) {
      const int m0 = mr*64 + i*16 + g*4;
      ushort4 pk;
      pk.x = f2b(va[i][jj][0]); pk.y = f2b(va[i][jj][1]);
      pk.z = f2b(va[i][jj][2]); pk.w = f2b(va[i][jj][3]);
      const int sl = m0 >> 3;
      *reinterpret_cast<ushort4*>(RB + j*128 + (((sl&8)|((sl&7)^(j&7)))<<3) + (m0&7)) = pk;
    }
  }
  #pragma unroll
  for (int i = 0; i < 4; ++i) {
    const int m = mr*64 + i*16 + l15;
    const float wd = exp2f((float)(C_ - 1 - m)*L2G);
    const int slm = m >> 3;
    #pragma unroll
    for (int jj = 0; jj < 4; ++jj) {
      #pragma unroll
      for (int r = 0; r < 4; ++r) {
        const int d = nq*64 + jj*16 + g*4 + r;
        XS[d*128 + (((slm&8)|((slm&7)^(d&7)))<<3) + (m&7)] = f2b(ka[i][jj][r] * wd);
      }
    }
  }
  __syncthreads();

  // ---- T9: T-GEMM  T[j][i] = sum_m VT[j,m]*KTw[i,m]  (l15=j, regs=consec i) ----
  const int ih = wid & 1, jq = wid >> 1;
  {
    f32x4 tt[8][4] = {};
    #pragma unroll
    for (int kk = 0; kk < 4; ++kk) {
      short8 fk[8], fv[4];
      #pragma unroll
      for (int ii = 0; ii < 8; ++ii) fk[ii] = fr16(XS, ih*128 + ii*16 + l15, kk*4 + g);
      #pragma unroll
      for (int jj = 0; jj < 4; ++jj) fv[jj] = fr16(RB, jq*64 + jj*16 + l15, kk*4 + g);
      #pragma unroll
      for (int ii = 0; ii < 8; ++ii)
        #pragma unroll
        for (int jj = 0; jj < 4; ++jj)
          tt[ii][jj] = mfma16(fk[ii], fv[jj], tt[ii][jj]);
    }
    __syncthreads();   // all KTw/VT reads done before XS reuse

    // VT global store (RB stable from here on)
    {
      const size_t vtb = ((size_t)(b*NC_ + c)) << 15;
      #pragma unroll
      for (int it = 0; it < 8; ++it) {
        const int u = it*512 + t, row = u >> 4, sl = u & 15;
        uint4 v = *reinterpret_cast<const uint4*>(RB + row*128 + (((sl&8)|((sl&7)^(row&7)))<<3));
        *reinterpret_cast<uint4*>(VTg + vtb + (size_t)row*128 + sl*8) = v;
      }
    }

    const size_t tb = ((size_t)(b*NC_ + c)) << 16;
    #pragma unroll
    for (int p = 0; p < 2; ++p) {
      if ((jq >> 1) == p) {
        #pragma unroll
        for (int ii = 0; ii < 8; ++ii)
          #pragma unroll
          for (int jj = 0; jj < 4; ++jj) {
            const int jl = (jq&1)*64 + jj*16 + l15;
            const int i0 = ih*128 + ii*16 + g*4;
            ushort4 pk;
            pk.x = f2b(tt[ii][jj][0]); pk.y = f2b(tt[ii][jj][1]);
            pk.z = f2b(tt[ii][jj][2]); pk.w = f2b(tt[ii][jj][3]);
            const int sl = i0 >> 3;
            *reinterpret_cast<ushort4*>(XS + jl*256 + (((sl&24)|((sl&7)^(jl&7)))<<3) + (i0&7)) = pk;
          }
      }
      __syncthreads();
      #pragma unroll
      for (int it = 0; it < 8; ++it) {
        const int u = it*512 + t, row = u >> 5, sl = u & 31;
        uint4 v = *reinterpret_cast<const uint4*>(XS + row*256 + (((sl&24)|((sl&7)^(row&7)))<<3));
        *reinterpret_cast<uint4*>(Tt + tb + (size_t)(p*128 + row)*256 + sl*8) = v;
      }
      __syncthreads();
    }
  }
}

// ---------------- K2: exclusive scan: state[c] = g^C state[c-1] + T[c-1] ----------------
__global__ __launch_bounds__(256) void scan_state(u16* __restrict__ Tt)
{
  const unsigned e = blockIdx.x*256u + threadIdx.x;   // B_*32768 threads, 2 elems each
  const unsigned b = e >> 15, el = (e & 32767u) << 1;
  const float gC = exp2f(128.0f * L2G);
  float r0 = 0.f, r1 = 0.f;
  const size_t base = (((size_t)b * NC_) << 16) + el;
  #pragma unroll
  for (int grp = 0; grp < 4; ++grp) {
    unsigned buf[16];
    #pragma unroll
    for (int i2 = 0; i2 < 16; ++i2)
      buf[i2] = *reinterpret_cast<const unsigned*>(Tt + base + (size_t)(grp*16 + i2)*65536);
    #pragma unroll
    for (int i2 = 0; i2 < 16; ++i2) {
      const unsigned v = buf[i2];
      *reinterpret_cast<unsigned*>(Tt + base + (size_t)(grp*16 + i2)*65536) =
          (unsigned)f2b(r0) | ((unsigned)f2b(r1) << 16);
      r0 = fmaf(gC, r0, b2f((u16)(v & 0xffff)));
      r1 = fmaf(gC, r1, b2f((u16)(v >> 16)));
    }
  }
}

// ---------------- K3: Out = g^(n+1)*(Q @ state) + Sc·V  (no Oloc round trip) ----------
__global__ __launch_bounds__(256) void out_kernel(
    const u16* __restrict__ Qh, const u16* __restrict__ Tt,
    const u16* __restrict__ Scg, const u16* __restrict__ VTg,
    float* __restrict__ Out)
{
  __shared__ u16 SM[32768];   // 64 KB -> 2 blocks/CU
  const int t = threadIdx.x, l = t & 63, wid = t >> 6;
  const int wr = wid >> 1, wc = wid & 1, g = l >> 4, l15 = l & 15;
  const int c = blockIdx.x, b = blockIdx.y, jh = blockIdx.z;
  const u16* Asrc = Qh + (size_t)(b*S_ + c*C_)*H_;
  const u16* Bsrc = Tt + (((size_t)(b*NC_ + c)) << 16) + (size_t)(jh*128)*H_;
  f32x4 acc[4][4] = {};

  // ---- phase A: cross GEMM (contraction over d=256) ----
  stageA(Asrc, H_, SM, 0, t);
  stageA(Bsrc, H_, SM, 8192, t);
  __syncthreads();
  for (int ks = 0; ks < 4; ++ks) {
    const int cur = (ks & 1) * 16384;
    if (ks < 3) {
      stageA(Asrc + (ks+1)*64, H_, SM, 16384 - cur, t);
      stageA(Bsrc + (ks+1)*64, H_, SM, 16384 - cur + 8192, t);
    }
    #pragma unroll
    for (int kb = 0; kb < 2; ++kb) {
      short8 fq[4], ft[4];
      #pragma unroll
      for (int i = 0; i < 4; ++i) fq[i] = fragr(SM + cur, wr*64 + i*16 + l15, kb*4 + g);
      #pragma unroll
      for (int j = 0; j < 4; ++j) ft[j] = fragr(SM + cur + 8192, wc*64 + j*16 + l15, kb*4 + g);
      #pragma unroll
      for (int i = 0; i < 4; ++i)
        #pragma unroll
        for (int j = 0; j < 4; ++j)
          acc[i][j] = mfma16(ft[j], fq[i], acc[i][j]);   // l15=n, regs=consec j
    }
    __syncthreads();
  }

  // ---- phase B staging: Sc [128 n][128 m], VT half [128 j][128 m] ----
  const u16* ScC = Scg + (((size_t)(b*NC_ + c)) << 14);
  const u16* VtC = VTg + (((size_t)(b*NC_ + c)) << 15) + (size_t)(jh*128)*128;
  stageA(ScC,      128, SM, 0,     t);
  stageA(VtC,      128, SM, 8192,  t);
  stageA(ScC + 64, 128, SM, 16384, t);
  stageA(VtC + 64, 128, SM, 24576, t);
  // scale cross term by gamma^(n_local+1) while loads fly
  #pragma unroll
  for (int i = 0; i < 4; ++i) {
    const float gn = exp2f((float)(wr*64 + i*16 + l15 + 1) * L2G);
    #pragma unroll
    for (int j = 0; j < 4; ++j)
      #pragma unroll
      for (int r = 0; r < 4; ++r) acc[i][j][r] *= gn;
  }
  __syncthreads();

  // ---- phase B: local GEMM (contraction over m=128) ----
  #pragma unroll
  for (int ks2 = 0; ks2 < 2; ++ks2) {
    #pragma unroll
    for (int kb = 0; kb < 2; ++kb) {
      short8 fs[4], fv[4];
      #pragma unroll
      for (int i = 0; i < 4; ++i)
        fs[i] = fragr(SM + ks2*16384, wr*64 + i*16 + l15, kb*4 + g);          // Sc rows n
      #pragma unroll
      for (int j = 0; j < 4; ++j)
        fv[j] = fragr(SM + ks2*16384 + 8192, wc*64 + j*16 + l15, kb*4 + g);   // VT rows j
      #pragma unroll
      for (int i = 0; i < 4; ++i)
        #pragma unroll
        for (int j = 0; j < 4; ++j)
          acc[i][j] = mfma16(fv[j], fs[i], acc[i][j]);
    }
  }
  __syncthreads();

  // ---- epilogue: restage [64 n][128 j] f32, coalesced Out store ----
  float* OL = reinterpret_cast<float*>(SM);
  for (int ph = 0; ph < 2; ++ph) {
    if (wr == ph) {
      #pragma unroll
      for (int i = 0; i < 4; ++i) {
        const int nl = i*16 + l15;
        #pragma unroll
        for (int j = 0; j < 4; ++j) {
          const int j0 = wc*64 + j*16 + g*4;
          const int sl = j0 >> 2;
          *reinterpret_cast<f32x4*>(OL + nl*128 + (((sl&24)|((sl&7)^(nl&7)))<<2)) = acc[i][j];
        }
      }
    }
    __syncthreads();
    #pragma unroll
    for (int it = 0; it < 8; ++it) {
      const int u = it*256 + t, nl = u >> 5, sl = u & 31;
      f32x4 v = *reinterpret_cast<const f32x4*>(OL + nl*128 + (((sl&24)|((sl&7)^(nl&7)))<<2));
      const size_t off = ((size_t)(b*S_ + c*C_ + ph*64 + nl))*256 + jh*128 + sl*4;
      *reinterpret_cast<f32x4*>(Out + off) = v;
    }
    __syncthreads();
  }
}

extern "C" void kernel_launch(void* const* d_in, const int* in_sizes, int n_in,
                              void* d_out, int out_size, void* d_ws, size_t ws_size,
                              hipStream_t stream) {
  const float* X  = (const float*)d_in[0];
  const float* Wq = (const float*)d_in[1];
  const float* Wk = (const float*)d_in[2];
  const float* Wv = (const float*)d_in[3];
  float* Out = (float*)d_out;
  u16* ws = (u16*)d_ws;
  // workspace (u16): WhT 196608 | RTab 4194304 | Qh 8388608 | Tt 16777216 | Scg 4194304 | VTg 8388608
  u16*   WhT  = ws;
  float* RTab = (float*)(ws + 196608);
  u16*   Qh   = ws + 196608 + 4194304;
  u16*   Tt   = Qh + (size_t)M_*H_;
  u16*   Scg  = Tt + (size_t)B_*NC_*65536;
  u16*   VTg  = Scg + (size_t)B_*NC_*16384;

  prep<<<96 + 4096, 256, 0, stream>>>(Wq, Wk, Wv, WhT, RTab);
  fused_chunk<<<dim3(NC_, B_), 512, 0, stream>>>(X, WhT, RTab, Qh, Tt, Scg, VTg);
  scan_state<<<(B_*32768)/256, 256, 0, stream>>>(Tt);
  out_kernel<<<dim3(NC_, B_, 2), 256, 0, stream>>>(Qh, Tt, Scg, VTg, Out);
}